// Round 14
// baseline (266.658 us; speedup 1.0000x reference)
//
#include <hip/hip_runtime.h>

// PQN soft-quantization: x[32768,1024] f32, c[1024,256] f32 -> out[32768,1024] f32
// D=1024, M=8 subspaces of L=128, K=256 codes, logits scaled by 2*ALPHA=20.
//
// R14: ZERO-LDS variant. R13 showed: all pipes <20% busy, occupancy 36%
// (LDS-capped 2 blocks/CU, effective 11.5 waves/CU), 80k cyc wall per 4k-cyc
// wave-iter => pure latency binding with too few waves. Fix: csB also streams
// from global/L2 (ws2 = f16 cast of c, c's layout IS [m][l][code]); no
// __shared__ at all -> 4 blocks x 512 thr/CU; at <=64 VGPR (R13 measured 60)
// the HW allows 8 waves/SIMD = 32 waves/CU.
// Phase 2 uses the same region-pipeline + sched_barrier(0) discipline as
// phase 1 and SHARES the two 4-fragment buffers (VGPR stays ~R13):
//   per chunk a: r0-r3 = p1 ks-steps (issue next ks, mfma current),
//   r3 issues p2 s0 (its latency hides under the softmax VALU),
//   r4-r7 = p2 sub-steps, r7 issues next chunk's p1 ks0 (wraps harmlessly).
// Grid 2048 x 512: one 16-sample wave-iter per wave, no barriers anywhere.
// rho row-permutation of ws1 makes packed exp words feed p2 B verbatim
// (unchanged, validated R8-R13).

#define D_  1024
#define K_  256
#define L_  128

typedef _Float16 f16;
typedef f16 f16x8 __attribute__((ext_vector_type(8)));
typedef f16 f16x4 __attribute__((ext_vector_type(4)));
typedef float f32x4 __attribute__((ext_vector_type(4)));
typedef unsigned int u32;

// prep A: c[(m*128+l)*256 + code] f32 -> ws1[m][rho(code)][l] f16 (512 KB)
__global__ __launch_bounds__(128)
void pqn_prep_rho(const float* __restrict__ c, f16* __restrict__ ws1) {
    const int b   = blockIdx.x;          // m*256 + code
    const int m   = b >> 8;
    const int cc  = b & 255;
    const int l   = threadIdx.x;         // 0..127
    const int rho = (cc & ~31) | ((cc & 4) << 2) | ((cc & 24) >> 1) | (cc & 3);
    float v = c[(size_t)(m * L_ + l) * K_ + cc];
    ws1[((size_t)m * K_ + rho) * L_ + l] = (f16)v;
}

// prep B: ws2 = (f16)c elementwise; c layout [m*128+l][code] == [m][l][code]
__global__ __launch_bounds__(256)
void pqn_prep_cast(const float* __restrict__ c, f16* __restrict__ ws2) {
    const int i = (blockIdx.x * 256 + threadIdx.x) * 4;   // 65536 threads x 4
    float4 v = *reinterpret_cast<const float4*>(c + i);
    f16x4 h = {(f16)v.x, (f16)v.y, (f16)v.z, (f16)v.w};
    *reinterpret_cast<f16x4*>(ws2 + i) = h;
}

__global__ __launch_bounds__(512)
void pqn_main(const float* __restrict__ x, const f16* __restrict__ ws1,
              const f16* __restrict__ ws2, float* __restrict__ out) {
    const int tid  = threadIdx.x;
    const int m    = blockIdx.x >> 8;    // 8 subspaces x 256 blocks
    const int bt   = blockIdx.x & 255;
    const int lane = tid & 63;
    const int w    = tid >> 6;           // wave 0..7
    const int n    = lane & 15;          // sample column
    const int g    = lane >> 4;          // quarter-wave (k-group)

    const int row0 = bt * 128 + w * 16 + n;

    // ---- x load + cvt to f16 fragments + row norm ----
    const float* px = x + (size_t)row0 * D_ + m * L_ + 8 * g;
    float ss = 0.f;
    f16x8 bf[4];
    #pragma unroll
    for (int ks = 0; ks < 4; ++ks) {
        float4 lo = *reinterpret_cast<const float4*>(px + 32 * ks);
        float4 hi = *reinterpret_cast<const float4*>(px + 32 * ks + 4);
        ss = fmaf(lo.x, lo.x, ss); ss = fmaf(lo.y, lo.y, ss);
        ss = fmaf(lo.z, lo.z, ss); ss = fmaf(lo.w, lo.w, ss);
        ss = fmaf(hi.x, hi.x, ss); ss = fmaf(hi.y, hi.y, ss);
        ss = fmaf(hi.z, hi.z, ss); ss = fmaf(hi.w, hi.w, ss);
        bf[ks][0] = (f16)lo.x; bf[ks][1] = (f16)lo.y;
        bf[ks][2] = (f16)lo.z; bf[ks][3] = (f16)lo.w;
        bf[ks][4] = (f16)hi.x; bf[ks][5] = (f16)hi.y;
        bf[ks][6] = (f16)hi.z; bf[ks][7] = (f16)hi.w;
    }
    ss += __shfl_xor(ss, 16);
    ss += __shfl_xor(ss, 32);
    const float fac = 20.0f / fmaxf(sqrtf(ss), 1e-12f);

    // lane bases into the two codebook tables
    const f16* wsa = ws1 + (size_t)m * (K_ * L_) + (size_t)n * L_ + 8 * g;  // [rho][l]
    const f16* wsb = ws2 + (size_t)m * (K_ * L_) + (size_t)n * K_ + 8 * g;  // [l][code]

    // ---- prime: bufA <- p1 chunk0 ks0 ----
    f16x8 bufA[4], bufB[4];
    #pragma unroll
    for (int ct = 0; ct < 4; ++ct)
        bufA[ct] = *reinterpret_cast<const f16x8*>(wsa + (ct * 16) * L_);

    f32x4 acc2[8];
    const f32x4 fzero = {0.f, 0.f, 0.f, 0.f};
    #pragma unroll
    for (int lt = 0; lt < 8; ++lt) acc2[lt] = fzero;
    float mrun = -3.0e38f;
    float sp   = 0.f;

    #pragma unroll 1
    for (int a = 0; a < 4; ++a) {
        const f16* wsc = wsa + (a * 64) * L_;
        f32x4 acc[4];
        #pragma unroll
        for (int ct = 0; ct < 4; ++ct) acc[ct] = fzero;

        // r0: issue p1 ks1 -> B; mfma p1 ks0 from A
        #pragma unroll
        for (int ct = 0; ct < 4; ++ct)
            bufB[ct] = *reinterpret_cast<const f16x8*>(wsc + (ct * 16) * L_ + 32);
        #pragma unroll
        for (int ct = 0; ct < 4; ++ct)
            acc[ct] = __builtin_amdgcn_mfma_f32_16x16x32_f16(bufA[ct], bf[0], acc[ct], 0, 0, 0);
        __builtin_amdgcn_sched_barrier(0);

        // r1: issue p1 ks2 -> A; mfma p1 ks1 from B
        #pragma unroll
        for (int ct = 0; ct < 4; ++ct)
            bufA[ct] = *reinterpret_cast<const f16x8*>(wsc + (ct * 16) * L_ + 64);
        #pragma unroll
        for (int ct = 0; ct < 4; ++ct)
            acc[ct] = __builtin_amdgcn_mfma_f32_16x16x32_f16(bufB[ct], bf[1], acc[ct], 0, 0, 0);
        __builtin_amdgcn_sched_barrier(0);

        // r2: issue p1 ks3 -> B; mfma p1 ks2 from A
        #pragma unroll
        for (int ct = 0; ct < 4; ++ct)
            bufB[ct] = *reinterpret_cast<const f16x8*>(wsc + (ct * 16) * L_ + 96);
        #pragma unroll
        for (int ct = 0; ct < 4; ++ct)
            acc[ct] = __builtin_amdgcn_mfma_f32_16x16x32_f16(bufA[ct], bf[2], acc[ct], 0, 0, 0);
        __builtin_amdgcn_sched_barrier(0);

        // r3: issue p2 s0 (lt 0-3, j0) -> A; mfma p1 ks3 from B
        #pragma unroll
        for (int i = 0; i < 4; ++i)
            bufA[i] = *reinterpret_cast<const f16x8*>(wsb + (size_t)(i * 16) * K_ + (2 * a) * 32);
        #pragma unroll
        for (int ct = 0; ct < 4; ++ct)
            acc[ct] = __builtin_amdgcn_mfma_f32_16x16x32_f16(bufB[ct], bf[3], acc[ct], 0, 0, 0);
        __builtin_amdgcn_sched_barrier(0);

        // ---- softmax chunk (covers p2 s0 load latency) ----
        float cmax = -3.0e38f;
        #pragma unroll
        for (int ct = 0; ct < 4; ++ct) {
            acc[ct][0] *= fac; acc[ct][1] *= fac;
            acc[ct][2] *= fac; acc[ct][3] *= fac;
            cmax = fmaxf(cmax, fmaxf(fmaxf(acc[ct][0], acc[ct][1]),
                                     fmaxf(acc[ct][2], acc[ct][3])));
        }
        cmax = fmaxf(cmax, __shfl_xor(cmax, 16));
        cmax = fmaxf(cmax, __shfl_xor(cmax, 32));
        const float mnew = fmaxf(mrun, cmax);
        const float r = __expf(mrun - mnew);
        mrun = mnew;
        sp *= r;
        #pragma unroll
        for (int lt = 0; lt < 8; ++lt) {
            acc2[lt][0] *= r; acc2[lt][1] *= r;
            acc2[lt][2] *= r; acc2[lt][3] *= r;
        }
        u32 P[8];
        #pragma unroll
        for (int ct = 0; ct < 4; ++ct) {
            float p0 = __expf(acc[ct][0] - mrun);
            float p1 = __expf(acc[ct][1] - mrun);
            float p2 = __expf(acc[ct][2] - mrun);
            float p3 = __expf(acc[ct][3] - mrun);
            sp += (p0 + p1) + (p2 + p3);
            P[2 * ct]     = __builtin_bit_cast(u32, __builtin_amdgcn_cvt_pkrtz(p0, p1));
            P[2 * ct + 1] = __builtin_bit_cast(u32, __builtin_amdgcn_cvt_pkrtz(p2, p3));
        }
        __builtin_amdgcn_sched_barrier(0);

        union { f16x8 v; u32 q[4]; } pb0, pb1;
        pb0.q[0] = P[0]; pb0.q[1] = P[1]; pb0.q[2] = P[2]; pb0.q[3] = P[3];
        pb1.q[0] = P[4]; pb1.q[1] = P[5]; pb1.q[2] = P[6]; pb1.q[3] = P[7];

        // r4: issue p2 s1 (lt 4-7, j0) -> B; mfma s0: acc2[0..3] += A . pb0
        #pragma unroll
        for (int i = 0; i < 4; ++i)
            bufB[i] = *reinterpret_cast<const f16x8*>(wsb + (size_t)((4 + i) * 16) * K_ + (2 * a) * 32);
        #pragma unroll
        for (int i = 0; i < 4; ++i)
            acc2[i] = __builtin_amdgcn_mfma_f32_16x16x32_f16(bufA[i], pb0.v, acc2[i], 0, 0, 0);
        __builtin_amdgcn_sched_barrier(0);

        // r5: issue p2 s2 (lt 0-3, j1) -> A; mfma s1: acc2[4..7] += B . pb0
        #pragma unroll
        for (int i = 0; i < 4; ++i)
            bufA[i] = *reinterpret_cast<const f16x8*>(wsb + (size_t)(i * 16) * K_ + (2 * a + 1) * 32);
        #pragma unroll
        for (int i = 0; i < 4; ++i)
            acc2[4 + i] = __builtin_amdgcn_mfma_f32_16x16x32_f16(bufB[i], pb0.v, acc2[4 + i], 0, 0, 0);
        __builtin_amdgcn_sched_barrier(0);

        // r6: issue p2 s3 (lt 4-7, j1) -> B; mfma s2: acc2[0..3] += A . pb1
        #pragma unroll
        for (int i = 0; i < 4; ++i)
            bufB[i] = *reinterpret_cast<const f16x8*>(wsb + (size_t)((4 + i) * 16) * K_ + (2 * a + 1) * 32);
        #pragma unroll
        for (int i = 0; i < 4; ++i)
            acc2[i] = __builtin_amdgcn_mfma_f32_16x16x32_f16(bufA[i], pb1.v, acc2[i], 0, 0, 0);
        __builtin_amdgcn_sched_barrier(0);

        // r7: issue next chunk's p1 ks0 -> A (wraps harmlessly on a=3);
        //     mfma s3: acc2[4..7] += B . pb1
        {
            const f16* wsn = wsa + (((a + 1) & 3) * 64) * L_;
            #pragma unroll
            for (int ct = 0; ct < 4; ++ct)
                bufA[ct] = *reinterpret_cast<const f16x8*>(wsn + (ct * 16) * L_);
        }
        #pragma unroll
        for (int i = 0; i < 4; ++i)
            acc2[4 + i] = __builtin_amdgcn_mfma_f32_16x16x32_f16(bufB[i], pb1.v, acc2[4 + i], 0, 0, 0);
        __builtin_amdgcn_sched_barrier(0);
    }

    // ---- final sum reduce + normalized store ----
    sp += __shfl_xor(sp, 16);
    sp += __shfl_xor(sp, 32);
    const float invS = 1.0f / sp;

    float* po = out + (size_t)row0 * D_ + m * L_ + 4 * g;
    #pragma unroll
    for (int lt = 0; lt < 8; ++lt) {
        f32x4 v;
        v[0] = acc2[lt][0] * invS; v[1] = acc2[lt][1] * invS;
        v[2] = acc2[lt][2] * invS; v[3] = acc2[lt][3] * invS;
        *reinterpret_cast<f32x4*>(po + 16 * lt) = v;
    }
}

extern "C" void kernel_launch(void* const* d_in, const int* in_sizes, int n_in,
                              void* d_out, int out_size, void* d_ws, size_t ws_size,
                              hipStream_t stream) {
    const float* x = (const float*)d_in[0];   // [32768, 1024] f32
    const float* c = (const float*)d_in[1];   // [1024, 256]   f32
    float* out = (float*)d_out;               // [32768, 1024] f32
    f16* ws1 = (f16*)d_ws;                    // 512 KB: [8][256 rho][128] f16
    f16* ws2 = ws1 + 8 * K_ * L_;             // 512 KB: [8][128 l][256 code] f16
    (void)in_sizes; (void)n_in; (void)out_size; (void)ws_size;

    pqn_prep_rho<<<dim3(2048), dim3(128), 0, stream>>>(c, ws1);
    pqn_prep_cast<<<dim3(256), dim3(256), 0, stream>>>(c, ws2);
    pqn_main<<<dim3(2048), dim3(512), 0, stream>>>(x, ws1, ws2, out);
}